// Round 15
// baseline (564.712 us; speedup 1.0000x reference)
//
#include <hip/hip_runtime.h>
#include <hip/hip_bf16.h>

#define NB   65536
#define KD   10
#define NG   20
#define NH   200     // KD*NG
#define NH1  400
#define NIN  784

#define TAU 3e-4     // margin below which the sample is recomputed exactly in f64

using short8 = __attribute__((ext_vector_type(8))) short;
using f32x4  = __attribute__((ext_vector_type(4))) float;

__device__ inline float bf2f(unsigned short u) {
  union { unsigned int i; float f; } x; x.i = ((unsigned int)u) << 16; return x.f;
}
__device__ inline unsigned short f2bf(float v) {
  __hip_bfloat16 b = __float2bfloat16(v);
  return *reinterpret_cast<unsigned short*>(&b);
}
// Truncation split: hi = top-16-bits of v (exact AND), lo = RNE(v - hi).
__device__ inline void split2(float v, unsigned short& h, unsigned short& l) {
  union { float f; unsigned int i; } u; u.f = v;
  const unsigned int hbits = u.i & 0xffff0000u;
  h = (unsigned short)(hbits >> 16);
  union { unsigned int i; float f; } w; w.i = hbits;
  l = f2bf(v - w.f);
}
__device__ inline void gload_lds16(const void* g, void* l) {
  __builtin_amdgcn_global_load_lds(
      (const __attribute__((address_space(1))) unsigned int*)g,
      (__attribute__((address_space(3))) unsigned int*)l, 16, 0, 0);
}

// LDS chunk-XOR swizzle (16B granularity within each 64B row) — validated R10.
#define KSWZ(lane) ((((lane) & 3) ^ (((lane) >> 3) & 3)) * 8)
#define CSW(lane)  (((((lane) >> 4) ^ (((lane) >> 1) & 3))) * 8)

// ---------------------------------------------------------------------------
// Stage 1 (8-wave, validated R14): h1 = relu(x @ W1^T + b1) -> split bf16.
// ---------------------------------------------------------------------------
__global__ __launch_bounds__(512) void gemm1_fused(
    const float* __restrict__ xf,
    const unsigned short* __restrict__ Bhi, const unsigned short* __restrict__ Blo,
    const float* __restrict__ bias,
    unsigned short* __restrict__ Ohi, unsigned short* __restrict__ Olo)
{
  __shared__ __align__(16) short As_hi[2][128][32];
  __shared__ __align__(16) short As_lo[2][128][32];
  __shared__ __align__(16) short Bs_hi[2][128][32];
  __shared__ __align__(16) short Bs_lo[2][128][32];
  const int tid = threadIdx.x;
  const int lane = tid & 63, wid = tid >> 6;      // wid 0..7
  const int wr = wid >> 2, wc = wid & 3;          // 2 x 4 wave grid
  const int bid = blockIdx.x;
  const int sw = (bid & 7) * 256 + (bid >> 3);    // XCD-bijective swizzle
  const int n0 = (sw & 3) * 128;
  const int m0 = (sw >> 2) * 128;
  const int rr = lane >> 2;
  const int kswz = KSWZ(lane);
  const int csw = CSW(lane);
  const int fr = lane & 15;
  const int arow = tid >> 3;                      // 0..63
  const int wbyte = ((tid & 7) * 8) ^ (((tid >> 4) & 3) << 4);  // swizzled A dest
  const int acol = (tid & 7) * 4;                 // linear k offset

  f32x4 acc[4][2];
  #pragma unroll
  for (int i = 0; i < 4; ++i)
    #pragma unroll
    for (int j = 0; j < 2; ++j) acc[i][j] = (f32x4){0.f, 0.f, 0.f, 0.f};

  float4 va0, va1;

  auto loadA = [&](int ks) {
    const int k0 = ks * 32;
    const int kk = k0 + acol;
    va0 = make_float4(0.f, 0.f, 0.f, 0.f);
    va1 = va0;
    if (kk < NIN) {
      va0 = *reinterpret_cast<const float4*>(xf + (size_t)(m0 + arow) * NIN + kk);
      va1 = *reinterpret_cast<const float4*>(xf + (size_t)(m0 + 64 + arow) * NIN + kk);
    }
  };
  auto stageB = [&](int ks, int buf) {
    const int k0 = ks * 32;
    #pragma unroll
    for (int c = 0; c < 2; ++c) {
      const int ch = wid * 2 + c;                 // 0..15
      if (ch < 8)
        gload_lds16(Bhi + (size_t)(n0 + ch * 16 + rr) * 800 + k0 + kswz,
                    (char*)&Bs_hi[buf][0][0] + ch * 1024);
      else
        gload_lds16(Blo + (size_t)(n0 + (ch - 8) * 16 + rr) * 800 + k0 + kswz,
                    (char*)&Bs_lo[buf][0][0] + (ch - 8) * 1024);
    }
  };
  auto writeA = [&](int buf) {
    char* bh = (char*)&As_hi[buf][0][0];
    char* bl = (char*)&As_lo[buf][0][0];
    short4 h, l;
    split2(va0.x, (unsigned short&)h.x, (unsigned short&)l.x);
    split2(va0.y, (unsigned short&)h.y, (unsigned short&)l.y);
    split2(va0.z, (unsigned short&)h.z, (unsigned short&)l.z);
    split2(va0.w, (unsigned short&)h.w, (unsigned short&)l.w);
    *reinterpret_cast<short4*>(bh + arow * 64 + wbyte) = h;
    *reinterpret_cast<short4*>(bl + arow * 64 + wbyte) = l;
    split2(va1.x, (unsigned short&)h.x, (unsigned short&)l.x);
    split2(va1.y, (unsigned short&)h.y, (unsigned short&)l.y);
    split2(va1.z, (unsigned short&)h.z, (unsigned short&)l.z);
    split2(va1.w, (unsigned short&)h.w, (unsigned short&)l.w);
    *reinterpret_cast<short4*>(bh + (64 + arow) * 64 + wbyte) = h;
    *reinterpret_cast<short4*>(bl + (64 + arow) * 64 + wbyte) = l;
  };

  stageB(0, 0);
  loadA(0);
  writeA(0);
  __syncthreads();

  for (int ks = 0; ks < 25; ++ks) {
    const int cur = ks & 1, nxt = cur ^ 1;
    const bool more = (ks + 1 < 25);
    if (more) {
      stageB(ks + 1, nxt);
      loadA(ks + 1);
    }
    short8 ah[4], al[4], bh[2], bl[2];
    #pragma unroll
    for (int i = 0; i < 4; ++i) {
      ah[i] = *reinterpret_cast<const short8*>(&As_hi[cur][wr * 64 + i * 16 + fr][csw]);
      al[i] = *reinterpret_cast<const short8*>(&As_lo[cur][wr * 64 + i * 16 + fr][csw]);
    }
    #pragma unroll
    for (int j = 0; j < 2; ++j) {
      bh[j] = *reinterpret_cast<const short8*>(&Bs_hi[cur][wc * 32 + j * 16 + fr][csw]);
      bl[j] = *reinterpret_cast<const short8*>(&Bs_lo[cur][wc * 32 + j * 16 + fr][csw]);
    }
    #pragma unroll
    for (int i = 0; i < 4; ++i)
      #pragma unroll
      for (int j = 0; j < 2; ++j) {
        acc[i][j] = __builtin_amdgcn_mfma_f32_16x16x32_bf16(ah[i], bh[j], acc[i][j], 0, 0, 0);
        acc[i][j] = __builtin_amdgcn_mfma_f32_16x16x32_bf16(al[i], bh[j], acc[i][j], 0, 0, 0);
        acc[i][j] = __builtin_amdgcn_mfma_f32_16x16x32_bf16(ah[i], bl[j], acc[i][j], 0, 0, 0);
      }
    if (more) writeA(nxt);
    __syncthreads();
  }

  #pragma unroll
  for (int j = 0; j < 2; ++j) {
    const int n = n0 + wc * 32 + j * 16 + (lane & 15);
    if (n >= NH1) continue;
    const float bn = bias[n];
    #pragma unroll
    for (int i = 0; i < 4; ++i) {
      const int mb = m0 + wr * 64 + i * 16 + (lane >> 4) * 4;
      #pragma unroll
      for (int r = 0; r < 4; ++r) {
        float v = fmaxf(acc[i][j][r] + bn, 0.f);
        unsigned short h, l;
        split2(v, h, l);
        Ohi[(size_t)(mb + r) * NH1 + n] = h;
        Olo[(size_t)(mb + r) * NH1 + n] = l;
      }
    }
  }
}

// ---------------------------------------------------------------------------
// Stage 2 (8-wave, NEW): z_e = h1 @ W2^T + b2. All four tiles staged via
// gload_lds (32 x 1KB chunks, 4/wave), double-buffered. 64 KB -> 43% occ.
// ---------------------------------------------------------------------------
__global__ __launch_bounds__(512) void gemm2_split(
    const unsigned short* __restrict__ Ahi, const unsigned short* __restrict__ Alo,
    const unsigned short* __restrict__ Bhi, const unsigned short* __restrict__ Blo,
    const unsigned short* __restrict__ zp, const float* __restrict__ bias,
    float* __restrict__ Of)
{
  __shared__ __align__(16) short As_hi[2][128][32];
  __shared__ __align__(16) short As_lo[2][128][32];
  __shared__ __align__(16) short Bs_hi[2][128][32];
  __shared__ __align__(16) short Bs_lo[2][128][32];
  const int tid = threadIdx.x;
  const int lane = tid & 63, wid = tid >> 6;
  const int wr = wid >> 2, wc = wid & 3;          // 2 x 4 wave grid
  const int bid = blockIdx.x;
  const int sw = (bid & 7) * 128 + (bid >> 3);
  const int n0 = (sw & 1) * 128;
  const int m0 = (sw >> 1) * 128;
  const int rr = lane >> 2;
  const int kswz = KSWZ(lane);
  const int csw = CSW(lane);
  const int fr = lane & 15;

  f32x4 acc[4][2];
  #pragma unroll
  for (int i = 0; i < 4; ++i)
    #pragma unroll
    for (int j = 0; j < 2; ++j) acc[i][j] = (f32x4){0.f, 0.f, 0.f, 0.f};

  auto stage = [&](int ks, int buf) {
    const int k0 = ks * 32;
    #pragma unroll
    for (int q = 0; q < 4; ++q) {
      const int c = wid * 4 + q;                  // 0..31
      const int tile = c >> 3, sub = c & 7;
      const unsigned short* G;
      char* Lt;
      int rbase, ld;
      if (tile == 0)      { G = Ahi; Lt = (char*)&As_hi[buf][0][0]; rbase = m0; ld = 400; }
      else if (tile == 1) { G = Alo; Lt = (char*)&As_lo[buf][0][0]; rbase = m0; ld = 400; }
      else if (tile == 2) { G = Bhi; Lt = (char*)&Bs_hi[buf][0][0]; rbase = n0; ld = 416; }
      else                { G = Blo; Lt = (char*)&Bs_lo[buf][0][0]; rbase = n0; ld = 416; }
      const unsigned short* src = G + (size_t)(rbase + sub * 16 + rr) * ld + k0 + kswz;
      if (tile < 2 && (k0 + kswz >= 400)) src = zp;   // A K-tail redirect
      gload_lds16(src, Lt + sub * 1024);
    }
  };

  stage(0, 0);
  __syncthreads();

  for (int ks = 0; ks < 13; ++ks) {
    const int cur = ks & 1;
    if (ks + 1 < 13) stage(ks + 1, cur ^ 1);
    short8 ah[4], al[4], bh[2], bl[2];
    #pragma unroll
    for (int i = 0; i < 4; ++i) {
      ah[i] = *reinterpret_cast<const short8*>(&As_hi[cur][wr * 64 + i * 16 + fr][csw]);
      al[i] = *reinterpret_cast<const short8*>(&As_lo[cur][wr * 64 + i * 16 + fr][csw]);
    }
    #pragma unroll
    for (int j = 0; j < 2; ++j) {
      bh[j] = *reinterpret_cast<const short8*>(&Bs_hi[cur][wc * 32 + j * 16 + fr][csw]);
      bl[j] = *reinterpret_cast<const short8*>(&Bs_lo[cur][wc * 32 + j * 16 + fr][csw]);
    }
    #pragma unroll
    for (int i = 0; i < 4; ++i)
      #pragma unroll
      for (int j = 0; j < 2; ++j) {
        acc[i][j] = __builtin_amdgcn_mfma_f32_16x16x32_bf16(ah[i], bh[j], acc[i][j], 0, 0, 0);
        acc[i][j] = __builtin_amdgcn_mfma_f32_16x16x32_bf16(al[i], bh[j], acc[i][j], 0, 0, 0);
        acc[i][j] = __builtin_amdgcn_mfma_f32_16x16x32_bf16(ah[i], bl[j], acc[i][j], 0, 0, 0);
      }
    __syncthreads();
  }

  #pragma unroll
  for (int j = 0; j < 2; ++j) {
    const int n = n0 + wc * 32 + j * 16 + (lane & 15);
    if (n >= NH) continue;
    const float bn = bias[n];
    #pragma unroll
    for (int i = 0; i < 4; ++i) {
      const int mb = m0 + wr * 64 + i * 16 + (lane >> 4) * 4;
      #pragma unroll
      for (int r = 0; r < 4; ++r)
        Of[(size_t)(mb + r) * NH + n] = acc[i][j][r] + bn;
    }
  }
}

// ---------------------------------------------------------------------------
// Stage 3 (8-wave, validated R14): h3 = relu(emb_bf @ W3p^T + b3) -> bf16.
// ---------------------------------------------------------------------------
__global__ __launch_bounds__(512) void gemm3_mfma(
    const unsigned short* __restrict__ A,   // emb_bf: NB x 200
    const __hip_bfloat16* __restrict__ Bp,  // W3p: 512 x 224
    const float* __restrict__ bias, __hip_bfloat16* __restrict__ H3)
{
  __shared__ __align__(16) short As[2][128][32];
  __shared__ __align__(16) short Bs[2][128][32];
  const int tid = threadIdx.x;
  const int lane = tid & 63, wid = tid >> 6;
  const int wr = wid >> 2, wc = wid & 3;
  const int bid = blockIdx.x;
  const int sw = (bid & 7) * 256 + (bid >> 3);
  const int n0 = (sw & 3) * 128;
  const int m0 = (sw >> 2) * 128;
  const int rr = lane >> 2;
  const int kswz = KSWZ(lane);
  const int csw = CSW(lane);
  const int fr = lane & 15;
  const short* Ag = (const short*)A;
  const short* Bg = (const short*)Bp;

  f32x4 acc[4][2];
  #pragma unroll
  for (int i = 0; i < 4; ++i)
    #pragma unroll
    for (int j = 0; j < 2; ++j) acc[i][j] = (f32x4){0.f, 0.f, 0.f, 0.f};

  auto stage = [&](int ks, int buf) {
    const int k0 = ks * 32;
    #pragma unroll
    for (int c = 0; c < 2; ++c) {
      const int ch = wid * 2 + c;
      if (ch < 8)
        gload_lds16(Ag + (size_t)(m0 + ch * 16 + rr) * 200 + k0 + kswz,
                    (char*)&As[buf][0][0] + ch * 1024);
      else
        gload_lds16(Bg + (size_t)(n0 + (ch - 8) * 16 + rr) * 224 + k0 + kswz,
                    (char*)&Bs[buf][0][0] + (ch - 8) * 1024);
    }
  };

  stage(0, 0);
  __syncthreads();
  for (int ks = 0; ks < 7; ++ks) {
    const int cur = ks & 1;
    if (ks + 1 < 7) stage(ks + 1, cur ^ 1);
    short8 af[4], bf[2];
    #pragma unroll
    for (int i = 0; i < 4; ++i)
      af[i] = *reinterpret_cast<const short8*>(&As[cur][wr * 64 + i * 16 + fr][csw]);
    #pragma unroll
    for (int j = 0; j < 2; ++j)
      bf[j] = *reinterpret_cast<const short8*>(&Bs[cur][wc * 32 + j * 16 + fr][csw]);
    #pragma unroll
    for (int i = 0; i < 4; ++i)
      #pragma unroll
      for (int j = 0; j < 2; ++j)
        acc[i][j] = __builtin_amdgcn_mfma_f32_16x16x32_bf16(af[i], bf[j], acc[i][j], 0, 0, 0);
    __syncthreads();
  }

  #pragma unroll
  for (int j = 0; j < 2; ++j) {
    const int n = n0 + wc * 32 + j * 16 + (lane & 15);
    if (n >= NH1) continue;
    const float bn = bias[n];
    #pragma unroll
    for (int i = 0; i < 4; ++i) {
      const int mb = m0 + wr * 64 + i * 16 + (lane >> 4) * 4;
      #pragma unroll
      for (int r = 0; r < 4; ++r)
        H3[(size_t)(mb + r) * NH1 + n] = __float2bfloat16(fmaxf(acc[i][j][r] + bn, 0.f));
    }
  }
}

// ---------------------------------------------------------------------------
// Stage 5 (8-wave, validated R14): recon = tanh(h3 @ W4p^T + b4).
// ---------------------------------------------------------------------------
__global__ __launch_bounds__(512) void gemm5_mfma(
    const __hip_bfloat16* __restrict__ A,   // h3: NB x 400
    const __hip_bfloat16* __restrict__ Bp,  // W4p: 896 x 416
    const float* __restrict__ bias, float* __restrict__ C)
{
  __shared__ __align__(16) short As[2][128][32];
  __shared__ __align__(16) short Bs[2][128][32];
  const int tid = threadIdx.x;
  const int lane = tid & 63, wid = tid >> 6;
  const int wr = wid >> 2, wc = wid & 3;
  const int bid = blockIdx.x;
  const int sw = (bid & 7) * 448 + (bid >> 3);
  const int n0 = (sw % 7) * 128;
  const int m0 = (sw / 7) * 128;
  const int rr = lane >> 2;
  const int kswz = KSWZ(lane);
  const int csw = CSW(lane);
  const int fr = lane & 15;
  const short* Ag = (const short*)A;
  const short* Bg = (const short*)Bp;

  f32x4 acc[4][2];
  #pragma unroll
  for (int i = 0; i < 4; ++i)
    #pragma unroll
    for (int j = 0; j < 2; ++j) acc[i][j] = (f32x4){0.f, 0.f, 0.f, 0.f};

  auto stage = [&](int ks, int buf) {
    const int k0 = ks * 32;
    #pragma unroll
    for (int c = 0; c < 2; ++c) {
      const int ch = wid * 2 + c;
      if (ch < 8)
        gload_lds16(Ag + (size_t)(m0 + ch * 16 + rr) * 400 + k0 + kswz,
                    (char*)&As[buf][0][0] + ch * 1024);
      else
        gload_lds16(Bg + (size_t)(n0 + (ch - 8) * 16 + rr) * 416 + k0 + kswz,
                    (char*)&Bs[buf][0][0] + (ch - 8) * 1024);
    }
  };

  stage(0, 0);
  __syncthreads();
  for (int ks = 0; ks < 13; ++ks) {
    const int cur = ks & 1;
    if (ks + 1 < 13) stage(ks + 1, cur ^ 1);
    short8 af[4], bf[2];
    #pragma unroll
    for (int i = 0; i < 4; ++i)
      af[i] = *reinterpret_cast<const short8*>(&As[cur][wr * 64 + i * 16 + fr][csw]);
    #pragma unroll
    for (int j = 0; j < 2; ++j)
      bf[j] = *reinterpret_cast<const short8*>(&Bs[cur][wc * 32 + j * 16 + fr][csw]);
    #pragma unroll
    for (int i = 0; i < 4; ++i)
      #pragma unroll
      for (int j = 0; j < 2; ++j)
        acc[i][j] = __builtin_amdgcn_mfma_f32_16x16x32_bf16(af[i], bf[j], acc[i][j], 0, 0, 0);
    __syncthreads();
  }

  #pragma unroll
  for (int j = 0; j < 2; ++j) {
    const int n = n0 + wc * 32 + j * 16 + (lane & 15);
    if (n >= NIN) continue;
    const float bn = bias[n];
    #pragma unroll
    for (int i = 0; i < 4; ++i) {
      const int mb = m0 + wr * 64 + i * 16 + (lane >> 4) * 4;
      #pragma unroll
      for (int r = 0; r < 4; ++r) {
        const float zv = acc[i][j][r] + bn;
        const float t = __expf(2.0f * zv);
        C[(size_t)(mb + r) * NIN + n] = 1.0f - __fdividef(2.0f, t + 1.0f);
      }
    }
  }
}

// ---------------------------------------------------------------------------
// Merged weight prep: W1/W2 split+pad, W4/W3 bf16+pad.
// ---------------------------------------------------------------------------
__global__ __launch_bounds__(256) void prep_all(
    const float* __restrict__ W1, const float* __restrict__ W2,
    const float* __restrict__ W3, const float* __restrict__ W4,
    unsigned short* __restrict__ W1ph, unsigned short* __restrict__ W1pl,
    unsigned short* __restrict__ W2ph, unsigned short* __restrict__ W2pl,
    __hip_bfloat16* __restrict__ W3p, __hip_bfloat16* __restrict__ W4p)
{
  const int i = blockIdx.x * 256 + threadIdx.x;
  if (i < 409600) {                       // W1p: 512 x 800
    const int n = i / 800, k = i % 800;
    const float v = (n < NH1 && k < NIN) ? W1[(size_t)n * NIN + k] : 0.f;
    unsigned short h, l; split2(v, h, l);
    W1ph[i] = h; W1pl[i] = l;
  } else if (i < 516096) {                // W2p: 256 x 416
    const int j = i - 409600;
    const int n = j / 416, k = j % 416;
    const float v = (n < NH && k < NH1) ? W2[(size_t)n * NH1 + k] : 0.f;
    unsigned short h, l; split2(v, h, l);
    W2ph[j] = h; W2pl[j] = l;
  } else if (i < 888832) {                // W4p: 896 x 416
    const int j = i - 516096;
    const int n = j / 416, k = j % 416;
    const float v = (n < NIN && k < NH1) ? W4[(size_t)n * NH1 + k] : 0.f;
    W4p[j] = __float2bfloat16(v);
  } else if (i < 1003520) {               // W3p: 512 x 224
    const int j = i - 888832;
    const int n = j / 224, k = j % 224;
    const float v = (n < NH1 && k < NH) ? W3[(size_t)n * NH + k] : 0.f;
    W3p[j] = __float2bfloat16(v);
  }
}

// ---------------------------------------------------------------------------
// Quantization (LDS-tiled, NEW): one block per 16 samples, 320 threads.
// Cooperative coalesced z_e load -> LDS; one group per thread; identical
// f64 argmin + margin flagging + inline compaction.
// ---------------------------------------------------------------------------
__global__ __launch_bounds__(320) void quant_kernel(
    const float* __restrict__ z_e, const float* __restrict__ cb,
    float* __restrict__ emb, unsigned short* __restrict__ ebf,
    unsigned int* __restrict__ sflag, int* __restrict__ scount,
    int* __restrict__ slist)
{
  __shared__ float zsl[16 * NH];
  __shared__ double cs[KD][KD];
  __shared__ double chalf[KD];
  __shared__ unsigned short cbf[KD][KD];
  const int tid = threadIdx.x;
  if (tid < KD * KD) {
    const double c = (double)cb[tid];
    cs[tid / KD][tid % KD] = c;
    cbf[tid / KD][tid % KD] = f2bf((float)c);
  }
  __syncthreads();
  if (tid < KD) {
    double s = 0.0;
    #pragma unroll
    for (int k = 0; k < KD; ++k) s += cs[tid][k] * cs[tid][k];
    chalf[tid] = 0.5 * s;
  }

  const int b0 = blockIdx.x * 16;
  for (int t = tid; t < 16 * NH; t += 320)
    zsl[t] = z_e[(size_t)b0 * NH + t];
  __syncthreads();

  const int s16 = tid / NG;           // 0..15
  const int g = tid % NG;
  const int b = b0 + s16;
  const float* zrow = &zsl[s16 * NH + g];
  double v[KD];
  #pragma unroll
  for (int k = 0; k < KD; ++k) v[k] = (double)zrow[k * NG];

  int best = 0; double bt = 1e300, bt2 = 1e300;
  #pragma unroll
  for (int j = 0; j < KD; ++j) {
    double t = chalf[j];
    #pragma unroll
    for (int k = 0; k < KD; ++k) t -= v[k] * cs[j][k];
    if (t < bt) { bt2 = bt; bt = t; best = j; }
    else if (t < bt2) { bt2 = t; }
  }
  float* ep = emb + (size_t)b * NH + g;
  unsigned short* eb = ebf + (size_t)b * NH + g;
  #pragma unroll
  for (int k = 0; k < KD; ++k) {
    ep[k * NG] = (float)cs[best][k];
    eb[k * NG] = cbf[best][k];
  }
  if (bt2 - bt < TAU) {
    if (atomicExch(&sflag[b], 1u) == 0u)
      slist[atomicAdd(scount, 1)] = b;
  }
}

// ---------------------------------------------------------------------------
// Exact f64 repair, one sample per block; rewrites emb + ebf.
// ---------------------------------------------------------------------------
__global__ __launch_bounds__(256) void repair_kernel(
    const float* __restrict__ x, const float* __restrict__ W1,
    const float* __restrict__ b1, const float* __restrict__ W2,
    const float* __restrict__ b2, const float* __restrict__ cb,
    const int* __restrict__ slist, const int* __restrict__ scount,
    float* __restrict__ emb, unsigned short* __restrict__ ebf)
{
  __shared__ double h1s[NH1];
  __shared__ double zs[NH];
  __shared__ double cs[KD][KD];
  __shared__ double chalf[KD];
  const int tid = threadIdx.x;
  const int lane = tid & 63, wv = tid >> 6;
  if (tid < KD * KD) cs[tid / KD][tid % KD] = (double)cb[tid];
  __syncthreads();
  if (tid < KD) {
    double s = 0.0;
    #pragma unroll
    for (int k = 0; k < KD; ++k) s += cs[tid][k] * cs[tid][k];
    chalf[tid] = 0.5 * s;
  }

  int S = *scount; if (S > NB) S = NB;

  for (int si = blockIdx.x; si < S; si += gridDim.x) {
    const int b = slist[si];
    double xr[4][4];
    #pragma unroll
    for (int it = 0; it < 4; ++it) {
      const int c4 = it * 64 + lane;
      if (c4 < 196) {
        float4 v = reinterpret_cast<const float4*>(x + (size_t)b * NIN)[c4];
        xr[it][0] = v.x; xr[it][1] = v.y; xr[it][2] = v.z; xr[it][3] = v.w;
      } else {
        xr[it][0] = xr[it][1] = xr[it][2] = xr[it][3] = 0.0;
      }
    }
    for (int j = wv; j < NH1; j += 4) {
      const float4* wr = reinterpret_cast<const float4*>(W1 + (size_t)j * NIN);
      double s0 = 0, s1 = 0, s2 = 0, s3 = 0;
      #pragma unroll
      for (int it = 0; it < 4; ++it) {
        const int c4 = it * 64 + lane;
        if (c4 < 196) {
          float4 w = wr[c4];
          s0 = fma(xr[it][0], (double)w.x, s0);
          s1 = fma(xr[it][1], (double)w.y, s1);
          s2 = fma(xr[it][2], (double)w.z, s2);
          s3 = fma(xr[it][3], (double)w.w, s3);
        }
      }
      double s = (s0 + s1) + (s2 + s3);
      #pragma unroll
      for (int off = 32; off > 0; off >>= 1) s += __shfl_down(s, off);
      if (lane == 0) { double h = s + (double)b1[j]; h1s[j] = h > 0.0 ? h : 0.0; }
    }
    __syncthreads();
    double hr[2][4];
    #pragma unroll
    for (int it = 0; it < 2; ++it) {
      const int c4 = it * 64 + lane;
      if (c4 < 100) {
        hr[it][0] = h1s[4 * c4 + 0]; hr[it][1] = h1s[4 * c4 + 1];
        hr[it][2] = h1s[4 * c4 + 2]; hr[it][3] = h1s[4 * c4 + 3];
      } else {
        hr[it][0] = hr[it][1] = hr[it][2] = hr[it][3] = 0.0;
      }
    }
    for (int n = wv; n < NH; n += 4) {
      const float4* wr = reinterpret_cast<const float4*>(W2 + (size_t)n * NH1);
      double s0 = 0, s1 = 0, s2 = 0, s3 = 0;
      #pragma unroll
      for (int it = 0; it < 2; ++it) {
        const int c4 = it * 64 + lane;
        if (c4 < 100) {
          float4 w = wr[c4];
          s0 = fma(hr[it][0], (double)w.x, s0);
          s1 = fma(hr[it][1], (double)w.y, s1);
          s2 = fma(hr[it][2], (double)w.z, s2);
          s3 = fma(hr[it][3], (double)w.w, s3);
        }
      }
      double s = (s0 + s1) + (s2 + s3);
      #pragma unroll
      for (int off = 32; off > 0; off >>= 1) s += __shfl_down(s, off);
      if (lane == 0) zs[n] = s + (double)b2[n];
    }
    __syncthreads();
    if (tid < NG) {
      const int g = tid;
      int best = 0; double bt = 1e300;
      #pragma unroll
      for (int j = 0; j < KD; ++j) {
        double t = chalf[j];
        #pragma unroll
        for (int k = 0; k < KD; ++k) t -= zs[k * NG + g] * cs[j][k];
        if (t < bt) { bt = t; best = j; }
      }
      #pragma unroll
      for (int k = 0; k < KD; ++k) {
        const float cv = (float)cs[best][k];
        emb[(size_t)b * NH + k * NG + g] = cv;
        ebf[(size_t)b * NH + k * NG + g] = f2bf(cv);
      }
    }
    __syncthreads();
  }
}

extern "C" void kernel_launch(void* const* d_in, const int* in_sizes, int n_in,
                              void* d_out, int out_size, void* d_ws, size_t ws_size,
                              hipStream_t stream) {
  const float* x  = (const float*)d_in[0];
  const float* W1 = (const float*)d_in[1];
  const float* b1 = (const float*)d_in[2];
  const float* W2 = (const float*)d_in[3];
  const float* b2 = (const float*)d_in[4];
  const float* W3 = (const float*)d_in[5];
  const float* b3 = (const float*)d_in[6];
  const float* W4 = (const float*)d_in[7];
  const float* b4 = (const float*)d_in[8];
  const float* cb = (const float*)d_in[9];

  float* out   = (float*)d_out;
  float* recon = out;                              // NB x 784 (written last)
  float* z_e   = out + (size_t)NB * NIN;           // NB x 200
  float* emb   = z_e + (size_t)NB * NH;            // NB x 200

  unsigned short* h1_lo  = (unsigned short*)emb;   // dead before quant writes emb
  unsigned short* emb_bf = (unsigned short*)recon; // dead recon region

  char* ws = (char*)d_ws;
  int*            scount = (int*)ws;                            // 4 B
  unsigned short* zp    = (unsigned short*)(ws + 256);          // 256 B zeros
  unsigned int*   sflag = (unsigned int*)(ws + 4096);           // 256 KB
  __hip_bfloat16* W3p   = (__hip_bfloat16*)(ws + (1u << 20));   // 512x224
  int*            slist = (int*)(ws + (4u << 20));              // 256 KB
  __hip_bfloat16* W4p   = (__hip_bfloat16*)(ws + (6u << 20));   // 896x416
  unsigned short* W1ph  = (unsigned short*)(ws + (7u << 20));   // 512x800
  unsigned short* W1pl  = (unsigned short*)(ws + (9u << 20));
  unsigned short* W2ph  = (unsigned short*)(ws + (11u << 20));  // 256x416
  unsigned short* W2pl  = (unsigned short*)(ws + (12u << 20));
  unsigned short* h1_hi = (unsigned short*)(ws + (16u << 20));  // NB x 400 bf16
  __hip_bfloat16* h3    = (__hip_bfloat16*)(ws + (16u << 20));  // reuses h1_hi (dead)

  dim3 blk(256);
  hipMemsetAsync(ws, 0, 4096 + NB * 4, stream);   // scount + zp + sflag(uint)
  prep_all<<<3920, blk, 0, stream>>>(W1, W2, W3, W4, W1ph, W1pl, W2ph, W2pl, W3p, W4p);

  // stage 1: h1 = relu(x @ W1^T + b1) -> split bf16 (8-wave, fused conversion)
  gemm1_fused<<<2048, dim3(512), 0, stream>>>(x, W1ph, W1pl, b1, h1_hi, h1_lo);
  // stage 2: z_e = h1 @ W2^T + b2 (8-wave)
  gemm2_split<<<1024, dim3(512), 0, stream>>>(h1_hi, h1_lo, W2ph, W2pl, zp, b2, z_e);

  // stage 3: quantize (LDS-tiled, +bf16 emb, inline compaction), repair
  quant_kernel<<<NB / 16, dim3(320), 0, stream>>>(z_e, cb, emb, emb_bf, sflag, scount, slist);
  repair_kernel<<<2048, blk, 0, stream>>>(x, W1, b1, W2, b2, cb, slist, scount, emb, emb_bf);

  // stage 4: h3 = relu(emb_bf @ W3p^T + b3) -> bf16 (8-wave)
  gemm3_mfma<<<2048, dim3(512), 0, stream>>>(emb_bf, W3p, b3, h3);
  // stage 5: recon = tanh(h3 @ W4p^T + b4) (8-wave)
  gemm5_mfma<<<3584, dim3(512), 0, stream>>>(h3, W4p, b4, recon);
}

// Round 16
// 555.394 us; speedup vs baseline: 1.0168x; 1.0168x over previous
//
#include <hip/hip_runtime.h>
#include <hip/hip_bf16.h>

#define NB   65536
#define KD   10
#define NG   20
#define NH   200     // KD*NG
#define NH1  400
#define NIN  784

#define TAU 3e-4     // margin below which the sample is recomputed exactly in f64

using short8 = __attribute__((ext_vector_type(8))) short;
using f32x4  = __attribute__((ext_vector_type(4))) float;

__device__ inline float bf2f(unsigned short u) {
  union { unsigned int i; float f; } x; x.i = ((unsigned int)u) << 16; return x.f;
}
__device__ inline unsigned short f2bf(float v) {
  __hip_bfloat16 b = __float2bfloat16(v);
  return *reinterpret_cast<unsigned short*>(&b);
}
// Truncation split: hi = top-16-bits of v (exact AND), lo = RNE(v - hi).
__device__ inline void split2(float v, unsigned short& h, unsigned short& l) {
  union { float f; unsigned int i; } u; u.f = v;
  const unsigned int hbits = u.i & 0xffff0000u;
  h = (unsigned short)(hbits >> 16);
  union { unsigned int i; float f; } w; w.i = hbits;
  l = f2bf(v - w.f);
}
__device__ inline void gload_lds16(const void* g, void* l) {
  __builtin_amdgcn_global_load_lds(
      (const __attribute__((address_space(1))) unsigned int*)g,
      (__attribute__((address_space(3))) unsigned int*)l, 16, 0, 0);
}

// LDS chunk-XOR swizzle (16B granularity within each 64B row) — validated R10.
#define KSWZ(lane) ((((lane) & 3) ^ (((lane) >> 3) & 3)) * 8)
#define CSW(lane)  (((((lane) >> 4) ^ (((lane) >> 1) & 3))) * 8)

// ---------------------------------------------------------------------------
// Stage 1 (8-wave, validated R14 + T5 setprio): h1 = relu(x@W1^T+b1) -> split.
// ---------------------------------------------------------------------------
__global__ __launch_bounds__(512) void gemm1_fused(
    const float* __restrict__ xf,
    const unsigned short* __restrict__ Bhi, const unsigned short* __restrict__ Blo,
    const float* __restrict__ bias,
    unsigned short* __restrict__ Ohi, unsigned short* __restrict__ Olo)
{
  __shared__ __align__(16) short As_hi[2][128][32];
  __shared__ __align__(16) short As_lo[2][128][32];
  __shared__ __align__(16) short Bs_hi[2][128][32];
  __shared__ __align__(16) short Bs_lo[2][128][32];
  const int tid = threadIdx.x;
  const int lane = tid & 63, wid = tid >> 6;
  const int wr = wid >> 2, wc = wid & 3;
  const int bid = blockIdx.x;
  const int sw = (bid & 7) * 256 + (bid >> 3);
  const int n0 = (sw & 3) * 128;
  const int m0 = (sw >> 2) * 128;
  const int rr = lane >> 2;
  const int kswz = KSWZ(lane);
  const int csw = CSW(lane);
  const int fr = lane & 15;
  const int arow = tid >> 3;
  const int wbyte = ((tid & 7) * 8) ^ (((tid >> 4) & 3) << 4);
  const int acol = (tid & 7) * 4;

  f32x4 acc[4][2];
  #pragma unroll
  for (int i = 0; i < 4; ++i)
    #pragma unroll
    for (int j = 0; j < 2; ++j) acc[i][j] = (f32x4){0.f, 0.f, 0.f, 0.f};

  float4 va0, va1;

  auto loadA = [&](int ks) {
    const int k0 = ks * 32;
    const int kk = k0 + acol;
    va0 = make_float4(0.f, 0.f, 0.f, 0.f);
    va1 = va0;
    if (kk < NIN) {
      va0 = *reinterpret_cast<const float4*>(xf + (size_t)(m0 + arow) * NIN + kk);
      va1 = *reinterpret_cast<const float4*>(xf + (size_t)(m0 + 64 + arow) * NIN + kk);
    }
  };
  auto stageB = [&](int ks, int buf) {
    const int k0 = ks * 32;
    #pragma unroll
    for (int c = 0; c < 2; ++c) {
      const int ch = wid * 2 + c;
      if (ch < 8)
        gload_lds16(Bhi + (size_t)(n0 + ch * 16 + rr) * 800 + k0 + kswz,
                    (char*)&Bs_hi[buf][0][0] + ch * 1024);
      else
        gload_lds16(Blo + (size_t)(n0 + (ch - 8) * 16 + rr) * 800 + k0 + kswz,
                    (char*)&Bs_lo[buf][0][0] + (ch - 8) * 1024);
    }
  };
  auto writeA = [&](int buf) {
    char* bh = (char*)&As_hi[buf][0][0];
    char* bl = (char*)&As_lo[buf][0][0];
    short4 h, l;
    split2(va0.x, (unsigned short&)h.x, (unsigned short&)l.x);
    split2(va0.y, (unsigned short&)h.y, (unsigned short&)l.y);
    split2(va0.z, (unsigned short&)h.z, (unsigned short&)l.z);
    split2(va0.w, (unsigned short&)h.w, (unsigned short&)l.w);
    *reinterpret_cast<short4*>(bh + arow * 64 + wbyte) = h;
    *reinterpret_cast<short4*>(bl + arow * 64 + wbyte) = l;
    split2(va1.x, (unsigned short&)h.x, (unsigned short&)l.x);
    split2(va1.y, (unsigned short&)h.y, (unsigned short&)l.y);
    split2(va1.z, (unsigned short&)h.z, (unsigned short&)l.z);
    split2(va1.w, (unsigned short&)h.w, (unsigned short&)l.w);
    *reinterpret_cast<short4*>(bh + (64 + arow) * 64 + wbyte) = h;
    *reinterpret_cast<short4*>(bl + (64 + arow) * 64 + wbyte) = l;
  };

  stageB(0, 0);
  loadA(0);
  writeA(0);
  __syncthreads();

  for (int ks = 0; ks < 25; ++ks) {
    const int cur = ks & 1, nxt = cur ^ 1;
    const bool more = (ks + 1 < 25);
    if (more) {
      stageB(ks + 1, nxt);
      loadA(ks + 1);
    }
    short8 ah[4], al[4], bh[2], bl[2];
    #pragma unroll
    for (int i = 0; i < 4; ++i) {
      ah[i] = *reinterpret_cast<const short8*>(&As_hi[cur][wr * 64 + i * 16 + fr][csw]);
      al[i] = *reinterpret_cast<const short8*>(&As_lo[cur][wr * 64 + i * 16 + fr][csw]);
    }
    #pragma unroll
    for (int j = 0; j < 2; ++j) {
      bh[j] = *reinterpret_cast<const short8*>(&Bs_hi[cur][wc * 32 + j * 16 + fr][csw]);
      bl[j] = *reinterpret_cast<const short8*>(&Bs_lo[cur][wc * 32 + j * 16 + fr][csw]);
    }
    __builtin_amdgcn_s_setprio(1);
    #pragma unroll
    for (int i = 0; i < 4; ++i)
      #pragma unroll
      for (int j = 0; j < 2; ++j) {
        acc[i][j] = __builtin_amdgcn_mfma_f32_16x16x32_bf16(ah[i], bh[j], acc[i][j], 0, 0, 0);
        acc[i][j] = __builtin_amdgcn_mfma_f32_16x16x32_bf16(al[i], bh[j], acc[i][j], 0, 0, 0);
        acc[i][j] = __builtin_amdgcn_mfma_f32_16x16x32_bf16(ah[i], bl[j], acc[i][j], 0, 0, 0);
      }
    __builtin_amdgcn_s_setprio(0);
    if (more) writeA(nxt);
    __syncthreads();
  }

  #pragma unroll
  for (int j = 0; j < 2; ++j) {
    const int n = n0 + wc * 32 + j * 16 + (lane & 15);
    if (n >= NH1) continue;
    const float bn = bias[n];
    #pragma unroll
    for (int i = 0; i < 4; ++i) {
      const int mb = m0 + wr * 64 + i * 16 + (lane >> 4) * 4;
      #pragma unroll
      for (int r = 0; r < 4; ++r) {
        float v = fmaxf(acc[i][j][r] + bn, 0.f);
        unsigned short h, l;
        split2(v, h, l);
        Ohi[(size_t)(mb + r) * NH1 + n] = h;
        Olo[(size_t)(mb + r) * NH1 + n] = l;
      }
    }
  }
}

// ---------------------------------------------------------------------------
// Stage 2 (8-wave + hoisted stage descriptors + T5): z_e = h1 @ W2^T + b2.
// ---------------------------------------------------------------------------
__global__ __launch_bounds__(512) void gemm2_split(
    const unsigned short* __restrict__ Ahi, const unsigned short* __restrict__ Alo,
    const unsigned short* __restrict__ Bhi, const unsigned short* __restrict__ Blo,
    const unsigned short* __restrict__ zp, const float* __restrict__ bias,
    float* __restrict__ Of)
{
  __shared__ __align__(16) short As_hi[2][128][32];
  __shared__ __align__(16) short As_lo[2][128][32];
  __shared__ __align__(16) short Bs_hi[2][128][32];
  __shared__ __align__(16) short Bs_lo[2][128][32];
  const int tid = threadIdx.x;
  const int lane = tid & 63, wid = tid >> 6;
  const int wr = wid >> 2, wc = wid & 3;
  const int bid = blockIdx.x;
  const int sw = (bid & 7) * 128 + (bid >> 3);
  const int n0 = (sw & 1) * 128;
  const int m0 = (sw >> 1) * 128;
  const int rr = lane >> 2;
  const int kswz = KSWZ(lane);
  const int csw = CSW(lane);
  const int fr = lane & 15;

  f32x4 acc[4][2];
  #pragma unroll
  for (int i = 0; i < 4; ++i)
    #pragma unroll
    for (int j = 0; j < 2; ++j) acc[i][j] = (f32x4){0.f, 0.f, 0.f, 0.f};

  // hoisted per-thread stage descriptors (4 chunks per thread's wave slot)
  const unsigned short* srcb[4];
  char* dstb[4];
  bool isAt[4];
  #pragma unroll
  for (int q = 0; q < 4; ++q) {
    const int c = wid * 4 + q;                    // 0..31
    const int tile = c >> 3, sub = c & 7;
    const unsigned short* G;
    int rbase, ld;
    if (tile == 0)      { G = Ahi; rbase = m0; ld = 400; }
    else if (tile == 1) { G = Alo; rbase = m0; ld = 400; }
    else if (tile == 2) { G = Bhi; rbase = n0; ld = 416; }
    else                { G = Blo; rbase = n0; ld = 416; }
    srcb[q] = G + (size_t)(rbase + sub * 16 + rr) * ld + kswz;
    char* Lt = (tile == 0) ? (char*)&As_hi[0][0][0] : (tile == 1) ? (char*)&As_lo[0][0][0]
             : (tile == 2) ? (char*)&Bs_hi[0][0][0] : (char*)&Bs_lo[0][0][0];
    dstb[q] = Lt + sub * 1024;
    isAt[q] = (tile < 2);
  }
  const bool tailz = (kswz >= 16);   // only step k0=384 has 384+kswz >= 400

  auto stage = [&](int ks, int buf) {
    const int k0 = ks * 32;
    const bool ztail = (k0 == 384) && tailz;
    #pragma unroll
    for (int q = 0; q < 4; ++q) {
      const unsigned short* src = srcb[q] + k0;
      if (isAt[q] && ztail) src = zp;
      gload_lds16(src, dstb[q] + buf * 8192);
    }
  };

  stage(0, 0);
  __syncthreads();

  for (int ks = 0; ks < 13; ++ks) {
    const int cur = ks & 1;
    if (ks + 1 < 13) stage(ks + 1, cur ^ 1);
    short8 ah[4], al[4], bh[2], bl[2];
    #pragma unroll
    for (int i = 0; i < 4; ++i) {
      ah[i] = *reinterpret_cast<const short8*>(&As_hi[cur][wr * 64 + i * 16 + fr][csw]);
      al[i] = *reinterpret_cast<const short8*>(&As_lo[cur][wr * 64 + i * 16 + fr][csw]);
    }
    #pragma unroll
    for (int j = 0; j < 2; ++j) {
      bh[j] = *reinterpret_cast<const short8*>(&Bs_hi[cur][wc * 32 + j * 16 + fr][csw]);
      bl[j] = *reinterpret_cast<const short8*>(&Bs_lo[cur][wc * 32 + j * 16 + fr][csw]);
    }
    __builtin_amdgcn_s_setprio(1);
    #pragma unroll
    for (int i = 0; i < 4; ++i)
      #pragma unroll
      for (int j = 0; j < 2; ++j) {
        acc[i][j] = __builtin_amdgcn_mfma_f32_16x16x32_bf16(ah[i], bh[j], acc[i][j], 0, 0, 0);
        acc[i][j] = __builtin_amdgcn_mfma_f32_16x16x32_bf16(al[i], bh[j], acc[i][j], 0, 0, 0);
        acc[i][j] = __builtin_amdgcn_mfma_f32_16x16x32_bf16(ah[i], bl[j], acc[i][j], 0, 0, 0);
      }
    __builtin_amdgcn_s_setprio(0);
    __syncthreads();
  }

  #pragma unroll
  for (int j = 0; j < 2; ++j) {
    const int n = n0 + wc * 32 + j * 16 + (lane & 15);
    if (n >= NH) continue;
    const float bn = bias[n];
    #pragma unroll
    for (int i = 0; i < 4; ++i) {
      const int mb = m0 + wr * 64 + i * 16 + (lane >> 4) * 4;
      #pragma unroll
      for (int r = 0; r < 4; ++r)
        Of[(size_t)(mb + r) * NH + n] = acc[i][j][r] + bn;
    }
  }
}

// ---------------------------------------------------------------------------
// Stage 3 (8-wave + T5): h3 = relu(emb_bf @ W3p^T + b3) -> bf16.
// ---------------------------------------------------------------------------
__global__ __launch_bounds__(512) void gemm3_mfma(
    const unsigned short* __restrict__ A,   // emb_bf: NB x 200
    const __hip_bfloat16* __restrict__ Bp,  // W3p: 512 x 224
    const float* __restrict__ bias, __hip_bfloat16* __restrict__ H3)
{
  __shared__ __align__(16) short As[2][128][32];
  __shared__ __align__(16) short Bs[2][128][32];
  const int tid = threadIdx.x;
  const int lane = tid & 63, wid = tid >> 6;
  const int wr = wid >> 2, wc = wid & 3;
  const int bid = blockIdx.x;
  const int sw = (bid & 7) * 256 + (bid >> 3);
  const int n0 = (sw & 3) * 128;
  const int m0 = (sw >> 2) * 128;
  const int rr = lane >> 2;
  const int kswz = KSWZ(lane);
  const int csw = CSW(lane);
  const int fr = lane & 15;
  const short* Ag = (const short*)A;
  const short* Bg = (const short*)Bp;

  f32x4 acc[4][2];
  #pragma unroll
  for (int i = 0; i < 4; ++i)
    #pragma unroll
    for (int j = 0; j < 2; ++j) acc[i][j] = (f32x4){0.f, 0.f, 0.f, 0.f};

  auto stage = [&](int ks, int buf) {
    const int k0 = ks * 32;
    #pragma unroll
    for (int c = 0; c < 2; ++c) {
      const int ch = wid * 2 + c;
      if (ch < 8)
        gload_lds16(Ag + (size_t)(m0 + ch * 16 + rr) * 200 + k0 + kswz,
                    (char*)&As[buf][0][0] + ch * 1024);
      else
        gload_lds16(Bg + (size_t)(n0 + (ch - 8) * 16 + rr) * 224 + k0 + kswz,
                    (char*)&Bs[buf][0][0] + (ch - 8) * 1024);
    }
  };

  stage(0, 0);
  __syncthreads();
  for (int ks = 0; ks < 7; ++ks) {
    const int cur = ks & 1;
    if (ks + 1 < 7) stage(ks + 1, cur ^ 1);
    short8 af[4], bf[2];
    #pragma unroll
    for (int i = 0; i < 4; ++i)
      af[i] = *reinterpret_cast<const short8*>(&As[cur][wr * 64 + i * 16 + fr][csw]);
    #pragma unroll
    for (int j = 0; j < 2; ++j)
      bf[j] = *reinterpret_cast<const short8*>(&Bs[cur][wc * 32 + j * 16 + fr][csw]);
    __builtin_amdgcn_s_setprio(1);
    #pragma unroll
    for (int i = 0; i < 4; ++i)
      #pragma unroll
      for (int j = 0; j < 2; ++j)
        acc[i][j] = __builtin_amdgcn_mfma_f32_16x16x32_bf16(af[i], bf[j], acc[i][j], 0, 0, 0);
    __builtin_amdgcn_s_setprio(0);
    __syncthreads();
  }

  #pragma unroll
  for (int j = 0; j < 2; ++j) {
    const int n = n0 + wc * 32 + j * 16 + (lane & 15);
    if (n >= NH1) continue;
    const float bn = bias[n];
    #pragma unroll
    for (int i = 0; i < 4; ++i) {
      const int mb = m0 + wr * 64 + i * 16 + (lane >> 4) * 4;
      #pragma unroll
      for (int r = 0; r < 4; ++r)
        H3[(size_t)(mb + r) * NH1 + n] = __float2bfloat16(fmaxf(acc[i][j][r] + bn, 0.f));
    }
  }
}

// ---------------------------------------------------------------------------
// Stage 5 (8-wave + T5): recon = tanh(h3 @ W4p^T + b4). Fast tanh.
// ---------------------------------------------------------------------------
__global__ __launch_bounds__(512) void gemm5_mfma(
    const __hip_bfloat16* __restrict__ A,   // h3: NB x 400
    const __hip_bfloat16* __restrict__ Bp,  // W4p: 896 x 416
    const float* __restrict__ bias, float* __restrict__ C)
{
  __shared__ __align__(16) short As[2][128][32];
  __shared__ __align__(16) short Bs[2][128][32];
  const int tid = threadIdx.x;
  const int lane = tid & 63, wid = tid >> 6;
  const int wr = wid >> 2, wc = wid & 3;
  const int bid = blockIdx.x;
  const int sw = (bid & 7) * 448 + (bid >> 3);
  const int n0 = (sw % 7) * 128;
  const int m0 = (sw / 7) * 128;
  const int rr = lane >> 2;
  const int kswz = KSWZ(lane);
  const int csw = CSW(lane);
  const int fr = lane & 15;
  const short* Ag = (const short*)A;
  const short* Bg = (const short*)Bp;

  f32x4 acc[4][2];
  #pragma unroll
  for (int i = 0; i < 4; ++i)
    #pragma unroll
    for (int j = 0; j < 2; ++j) acc[i][j] = (f32x4){0.f, 0.f, 0.f, 0.f};

  auto stage = [&](int ks, int buf) {
    const int k0 = ks * 32;
    #pragma unroll
    for (int c = 0; c < 2; ++c) {
      const int ch = wid * 2 + c;
      if (ch < 8)
        gload_lds16(Ag + (size_t)(m0 + ch * 16 + rr) * 400 + k0 + kswz,
                    (char*)&As[buf][0][0] + ch * 1024);
      else
        gload_lds16(Bg + (size_t)(n0 + (ch - 8) * 16 + rr) * 416 + k0 + kswz,
                    (char*)&Bs[buf][0][0] + (ch - 8) * 1024);
    }
  };

  stage(0, 0);
  __syncthreads();
  for (int ks = 0; ks < 13; ++ks) {
    const int cur = ks & 1;
    if (ks + 1 < 13) stage(ks + 1, cur ^ 1);
    short8 af[4], bf[2];
    #pragma unroll
    for (int i = 0; i < 4; ++i)
      af[i] = *reinterpret_cast<const short8*>(&As[cur][wr * 64 + i * 16 + fr][csw]);
    #pragma unroll
    for (int j = 0; j < 2; ++j)
      bf[j] = *reinterpret_cast<const short8*>(&Bs[cur][wc * 32 + j * 16 + fr][csw]);
    __builtin_amdgcn_s_setprio(1);
    #pragma unroll
    for (int i = 0; i < 4; ++i)
      #pragma unroll
      for (int j = 0; j < 2; ++j)
        acc[i][j] = __builtin_amdgcn_mfma_f32_16x16x32_bf16(af[i], bf[j], acc[i][j], 0, 0, 0);
    __builtin_amdgcn_s_setprio(0);
    __syncthreads();
  }

  #pragma unroll
  for (int j = 0; j < 2; ++j) {
    const int n = n0 + wc * 32 + j * 16 + (lane & 15);
    if (n >= NIN) continue;
    const float bn = bias[n];
    #pragma unroll
    for (int i = 0; i < 4; ++i) {
      const int mb = m0 + wr * 64 + i * 16 + (lane >> 4) * 4;
      #pragma unroll
      for (int r = 0; r < 4; ++r) {
        const float zv = acc[i][j][r] + bn;
        const float t = __expf(2.0f * zv);
        C[(size_t)(mb + r) * NIN + n] = 1.0f - __fdividef(2.0f, t + 1.0f);
      }
    }
  }
}

// ---------------------------------------------------------------------------
// Merged weight prep: W1/W2 split+pad, W4/W3 bf16+pad.
// ---------------------------------------------------------------------------
__global__ __launch_bounds__(256) void prep_all(
    const float* __restrict__ W1, const float* __restrict__ W2,
    const float* __restrict__ W3, const float* __restrict__ W4,
    unsigned short* __restrict__ W1ph, unsigned short* __restrict__ W1pl,
    unsigned short* __restrict__ W2ph, unsigned short* __restrict__ W2pl,
    __hip_bfloat16* __restrict__ W3p, __hip_bfloat16* __restrict__ W4p)
{
  const int i = blockIdx.x * 256 + threadIdx.x;
  if (i < 409600) {                       // W1p: 512 x 800
    const int n = i / 800, k = i % 800;
    const float v = (n < NH1 && k < NIN) ? W1[(size_t)n * NIN + k] : 0.f;
    unsigned short h, l; split2(v, h, l);
    W1ph[i] = h; W1pl[i] = l;
  } else if (i < 516096) {                // W2p: 256 x 416
    const int j = i - 409600;
    const int n = j / 416, k = j % 416;
    const float v = (n < NH && k < NH1) ? W2[(size_t)n * NH1 + k] : 0.f;
    unsigned short h, l; split2(v, h, l);
    W2ph[j] = h; W2pl[j] = l;
  } else if (i < 888832) {                // W4p: 896 x 416
    const int j = i - 516096;
    const int n = j / 416, k = j % 416;
    const float v = (n < NIN && k < NH1) ? W4[(size_t)n * NH1 + k] : 0.f;
    W4p[j] = __float2bfloat16(v);
  } else if (i < 1003520) {               // W3p: 512 x 224
    const int j = i - 888832;
    const int n = j / 224, k = j % 224;
    const float v = (n < NH1 && k < NH) ? W3[(size_t)n * NH + k] : 0.f;
    W3p[j] = __float2bfloat16(v);
  }
}

// ---------------------------------------------------------------------------
// Quantization (LDS-tiled): one block per 16 samples, 320 threads.
// ---------------------------------------------------------------------------
__global__ __launch_bounds__(320) void quant_kernel(
    const float* __restrict__ z_e, const float* __restrict__ cb,
    float* __restrict__ emb, unsigned short* __restrict__ ebf,
    unsigned int* __restrict__ sflag, int* __restrict__ scount,
    int* __restrict__ slist)
{
  __shared__ float zsl[16 * NH];
  __shared__ double cs[KD][KD];
  __shared__ double chalf[KD];
  __shared__ unsigned short cbf[KD][KD];
  const int tid = threadIdx.x;
  if (tid < KD * KD) {
    const double c = (double)cb[tid];
    cs[tid / KD][tid % KD] = c;
    cbf[tid / KD][tid % KD] = f2bf((float)c);
  }
  __syncthreads();
  if (tid < KD) {
    double s = 0.0;
    #pragma unroll
    for (int k = 0; k < KD; ++k) s += cs[tid][k] * cs[tid][k];
    chalf[tid] = 0.5 * s;
  }

  const int b0 = blockIdx.x * 16;
  for (int t = tid; t < 16 * NH; t += 320)
    zsl[t] = z_e[(size_t)b0 * NH + t];
  __syncthreads();

  const int s16 = tid / NG;           // 0..15
  const int g = tid % NG;
  const int b = b0 + s16;
  const float* zrow = &zsl[s16 * NH + g];
  double v[KD];
  #pragma unroll
  for (int k = 0; k < KD; ++k) v[k] = (double)zrow[k * NG];

  int best = 0; double bt = 1e300, bt2 = 1e300;
  #pragma unroll
  for (int j = 0; j < KD; ++j) {
    double t = chalf[j];
    #pragma unroll
    for (int k = 0; k < KD; ++k) t -= v[k] * cs[j][k];
    if (t < bt) { bt2 = bt; bt = t; best = j; }
    else if (t < bt2) { bt2 = t; }
  }
  float* ep = emb + (size_t)b * NH + g;
  unsigned short* eb = ebf + (size_t)b * NH + g;
  #pragma unroll
  for (int k = 0; k < KD; ++k) {
    ep[k * NG] = (float)cs[best][k];
    eb[k * NG] = cbf[best][k];
  }
  if (bt2 - bt < TAU) {
    if (atomicExch(&sflag[b], 1u) == 0u)
      slist[atomicAdd(scount, 1)] = b;
  }
}

// ---------------------------------------------------------------------------
// Exact f64 repair, one sample per block; rewrites emb + ebf.
// ---------------------------------------------------------------------------
__global__ __launch_bounds__(256) void repair_kernel(
    const float* __restrict__ x, const float* __restrict__ W1,
    const float* __restrict__ b1, const float* __restrict__ W2,
    const float* __restrict__ b2, const float* __restrict__ cb,
    const int* __restrict__ slist, const int* __restrict__ scount,
    float* __restrict__ emb, unsigned short* __restrict__ ebf)
{
  __shared__ double h1s[NH1];
  __shared__ double zs[NH];
  __shared__ double cs[KD][KD];
  __shared__ double chalf[KD];
  const int tid = threadIdx.x;
  const int lane = tid & 63, wv = tid >> 6;
  if (tid < KD * KD) cs[tid / KD][tid % KD] = (double)cb[tid];
  __syncthreads();
  if (tid < KD) {
    double s = 0.0;
    #pragma unroll
    for (int k = 0; k < KD; ++k) s += cs[tid][k] * cs[tid][k];
    chalf[tid] = 0.5 * s;
  }

  int S = *scount; if (S > NB) S = NB;

  for (int si = blockIdx.x; si < S; si += gridDim.x) {
    const int b = slist[si];
    double xr[4][4];
    #pragma unroll
    for (int it = 0; it < 4; ++it) {
      const int c4 = it * 64 + lane;
      if (c4 < 196) {
        float4 v = reinterpret_cast<const float4*>(x + (size_t)b * NIN)[c4];
        xr[it][0] = v.x; xr[it][1] = v.y; xr[it][2] = v.z; xr[it][3] = v.w;
      } else {
        xr[it][0] = xr[it][1] = xr[it][2] = xr[it][3] = 0.0;
      }
    }
    for (int j = wv; j < NH1; j += 4) {
      const float4* wr = reinterpret_cast<const float4*>(W1 + (size_t)j * NIN);
      double s0 = 0, s1 = 0, s2 = 0, s3 = 0;
      #pragma unroll
      for (int it = 0; it < 4; ++it) {
        const int c4 = it * 64 + lane;
        if (c4 < 196) {
          float4 w = wr[c4];
          s0 = fma(xr[it][0], (double)w.x, s0);
          s1 = fma(xr[it][1], (double)w.y, s1);
          s2 = fma(xr[it][2], (double)w.z, s2);
          s3 = fma(xr[it][3], (double)w.w, s3);
        }
      }
      double s = (s0 + s1) + (s2 + s3);
      #pragma unroll
      for (int off = 32; off > 0; off >>= 1) s += __shfl_down(s, off);
      if (lane == 0) { double h = s + (double)b1[j]; h1s[j] = h > 0.0 ? h : 0.0; }
    }
    __syncthreads();
    double hr[2][4];
    #pragma unroll
    for (int it = 0; it < 2; ++it) {
      const int c4 = it * 64 + lane;
      if (c4 < 100) {
        hr[it][0] = h1s[4 * c4 + 0]; hr[it][1] = h1s[4 * c4 + 1];
        hr[it][2] = h1s[4 * c4 + 2]; hr[it][3] = h1s[4 * c4 + 3];
      } else {
        hr[it][0] = hr[it][1] = hr[it][2] = hr[it][3] = 0.0;
      }
    }
    for (int n = wv; n < NH; n += 4) {
      const float4* wr = reinterpret_cast<const float4*>(W2 + (size_t)n * NH1);
      double s0 = 0, s1 = 0, s2 = 0, s3 = 0;
      #pragma unroll
      for (int it = 0; it < 2; ++it) {
        const int c4 = it * 64 + lane;
        if (c4 < 100) {
          float4 w = wr[c4];
          s0 = fma(hr[it][0], (double)w.x, s0);
          s1 = fma(hr[it][1], (double)w.y, s1);
          s2 = fma(hr[it][2], (double)w.z, s2);
          s3 = fma(hr[it][3], (double)w.w, s3);
        }
      }
      double s = (s0 + s1) + (s2 + s3);
      #pragma unroll
      for (int off = 32; off > 0; off >>= 1) s += __shfl_down(s, off);
      if (lane == 0) zs[n] = s + (double)b2[n];
    }
    __syncthreads();
    if (tid < NG) {
      const int g = tid;
      int best = 0; double bt = 1e300;
      #pragma unroll
      for (int j = 0; j < KD; ++j) {
        double t = chalf[j];
        #pragma unroll
        for (int k = 0; k < KD; ++k) t -= zs[k * NG + g] * cs[j][k];
        if (t < bt) { bt = t; best = j; }
      }
      #pragma unroll
      for (int k = 0; k < KD; ++k) {
        const float cv = (float)cs[best][k];
        emb[(size_t)b * NH + k * NG + g] = cv;
        ebf[(size_t)b * NH + k * NG + g] = f2bf(cv);
      }
    }
    __syncthreads();
  }
}

extern "C" void kernel_launch(void* const* d_in, const int* in_sizes, int n_in,
                              void* d_out, int out_size, void* d_ws, size_t ws_size,
                              hipStream_t stream) {
  const float* x  = (const float*)d_in[0];
  const float* W1 = (const float*)d_in[1];
  const float* b1 = (const float*)d_in[2];
  const float* W2 = (const float*)d_in[3];
  const float* b2 = (const float*)d_in[4];
  const float* W3 = (const float*)d_in[5];
  const float* b3 = (const float*)d_in[6];
  const float* W4 = (const float*)d_in[7];
  const float* b4 = (const float*)d_in[8];
  const float* cb = (const float*)d_in[9];

  float* out   = (float*)d_out;
  float* recon = out;                              // NB x 784 (written last)
  float* z_e   = out + (size_t)NB * NIN;           // NB x 200
  float* emb   = z_e + (size_t)NB * NH;            // NB x 200

  unsigned short* h1_lo  = (unsigned short*)emb;   // dead before quant writes emb
  unsigned short* emb_bf = (unsigned short*)recon; // dead recon region

  char* ws = (char*)d_ws;
  int*            scount = (int*)ws;                            // 4 B
  unsigned short* zp    = (unsigned short*)(ws + 256);          // 256 B zeros
  unsigned int*   sflag = (unsigned int*)(ws + 4096);           // 256 KB
  __hip_bfloat16* W3p   = (__hip_bfloat16*)(ws + (1u << 20));   // 512x224
  int*            slist = (int*)(ws + (4u << 20));              // 256 KB
  __hip_bfloat16* W4p   = (__hip_bfloat16*)(ws + (6u << 20));   // 896x416
  unsigned short* W1ph  = (unsigned short*)(ws + (7u << 20));   // 512x800
  unsigned short* W1pl  = (unsigned short*)(ws + (9u << 20));
  unsigned short* W2ph  = (unsigned short*)(ws + (11u << 20));  // 256x416
  unsigned short* W2pl  = (unsigned short*)(ws + (12u << 20));
  unsigned short* h1_hi = (unsigned short*)(ws + (16u << 20));  // NB x 400 bf16
  __hip_bfloat16* h3    = (__hip_bfloat16*)(ws + (16u << 20));  // reuses h1_hi (dead)

  dim3 blk(256);
  hipMemsetAsync(ws, 0, 4096 + NB * 4, stream);   // scount + zp + sflag(uint)
  prep_all<<<3920, blk, 0, stream>>>(W1, W2, W3, W4, W1ph, W1pl, W2ph, W2pl, W3p, W4p);

  // stage 1: h1 = relu(x @ W1^T + b1) -> split bf16 (8-wave, fused conversion)
  gemm1_fused<<<2048, dim3(512), 0, stream>>>(x, W1ph, W1pl, b1, h1_hi, h1_lo);
  // stage 2: z_e = h1 @ W2^T + b2 (8-wave)
  gemm2_split<<<1024, dim3(512), 0, stream>>>(h1_hi, h1_lo, W2ph, W2pl, zp, b2, z_e);

  // stage 3: quantize (LDS-tiled, +bf16 emb, inline compaction), repair
  quant_kernel<<<NB / 16, dim3(320), 0, stream>>>(z_e, cb, emb, emb_bf, sflag, scount, slist);
  repair_kernel<<<2048, blk, 0, stream>>>(x, W1, b1, W2, b2, cb, slist, scount, emb, emb_bf);

  // stage 4: h3 = relu(emb_bf @ W3p^T + b3) -> bf16 (8-wave)
  gemm3_mfma<<<2048, dim3(512), 0, stream>>>(emb_bf, W3p, b3, h3);
  // stage 5: recon = tanh(h3 @ W4p^T + b4) (8-wave)
  gemm5_mfma<<<3584, dim3(512), 0, stream>>>(h3, W4p, b4, recon);
}

// Round 17
// 555.006 us; speedup vs baseline: 1.0175x; 1.0007x over previous
//
#include <hip/hip_runtime.h>
#include <hip/hip_bf16.h>

#define NB   65536
#define KD   10
#define NG   20
#define NH   200     // KD*NG
#define NH1  400
#define NIN  784

#define TAU 3e-4     // margin below which the sample is recomputed exactly in f64

using short8 = __attribute__((ext_vector_type(8))) short;
using f32x4  = __attribute__((ext_vector_type(4))) float;

__device__ inline float bf2f(unsigned short u) {
  union { unsigned int i; float f; } x; x.i = ((unsigned int)u) << 16; return x.f;
}
__device__ inline unsigned short f2bf(float v) {
  __hip_bfloat16 b = __float2bfloat16(v);
  return *reinterpret_cast<unsigned short*>(&b);
}
// Truncation split: hi = top-16-bits of v (exact AND), lo = RNE(v - hi).
__device__ inline void split2(float v, unsigned short& h, unsigned short& l) {
  union { float f; unsigned int i; } u; u.f = v;
  const unsigned int hbits = u.i & 0xffff0000u;
  h = (unsigned short)(hbits >> 16);
  union { unsigned int i; float f; } w; w.i = hbits;
  l = f2bf(v - w.f);
}
__device__ inline void gload_lds16(const void* g, void* l) {
  __builtin_amdgcn_global_load_lds(
      (const __attribute__((address_space(1))) unsigned int*)g,
      (__attribute__((address_space(3))) unsigned int*)l, 16, 0, 0);
}

// LDS chunk-XOR swizzle (16B granularity within each 64B row) — validated R10.
#define KSWZ(lane) ((((lane) & 3) ^ (((lane) >> 3) & 3)) * 8)
#define CSW(lane)  (((((lane) >> 4) ^ (((lane) >> 1) & 3))) * 8)

// ---------------------------------------------------------------------------
// Stage 1 (8-wave + T5, validated R14/R16): h1 = relu(x@W1^T+b1) -> split.
// ---------------------------------------------------------------------------
__global__ __launch_bounds__(512) void gemm1_fused(
    const float* __restrict__ xf,
    const unsigned short* __restrict__ Bhi, const unsigned short* __restrict__ Blo,
    const float* __restrict__ bias,
    unsigned short* __restrict__ Ohi, unsigned short* __restrict__ Olo)
{
  __shared__ __align__(16) short As_hi[2][128][32];
  __shared__ __align__(16) short As_lo[2][128][32];
  __shared__ __align__(16) short Bs_hi[2][128][32];
  __shared__ __align__(16) short Bs_lo[2][128][32];
  const int tid = threadIdx.x;
  const int lane = tid & 63, wid = tid >> 6;
  const int wr = wid >> 2, wc = wid & 3;
  const int bid = blockIdx.x;
  const int sw = (bid & 7) * 256 + (bid >> 3);
  const int n0 = (sw & 3) * 128;
  const int m0 = (sw >> 2) * 128;
  const int rr = lane >> 2;
  const int kswz = KSWZ(lane);
  const int csw = CSW(lane);
  const int fr = lane & 15;
  const int arow = tid >> 3;
  const int wbyte = ((tid & 7) * 8) ^ (((tid >> 4) & 3) << 4);
  const int acol = (tid & 7) * 4;

  f32x4 acc[4][2];
  #pragma unroll
  for (int i = 0; i < 4; ++i)
    #pragma unroll
    for (int j = 0; j < 2; ++j) acc[i][j] = (f32x4){0.f, 0.f, 0.f, 0.f};

  float4 va0, va1;

  auto loadA = [&](int ks) {
    const int k0 = ks * 32;
    const int kk = k0 + acol;
    va0 = make_float4(0.f, 0.f, 0.f, 0.f);
    va1 = va0;
    if (kk < NIN) {
      va0 = *reinterpret_cast<const float4*>(xf + (size_t)(m0 + arow) * NIN + kk);
      va1 = *reinterpret_cast<const float4*>(xf + (size_t)(m0 + 64 + arow) * NIN + kk);
    }
  };
  auto stageB = [&](int ks, int buf) {
    const int k0 = ks * 32;
    #pragma unroll
    for (int c = 0; c < 2; ++c) {
      const int ch = wid * 2 + c;
      if (ch < 8)
        gload_lds16(Bhi + (size_t)(n0 + ch * 16 + rr) * 800 + k0 + kswz,
                    (char*)&Bs_hi[buf][0][0] + ch * 1024);
      else
        gload_lds16(Blo + (size_t)(n0 + (ch - 8) * 16 + rr) * 800 + k0 + kswz,
                    (char*)&Bs_lo[buf][0][0] + (ch - 8) * 1024);
    }
  };
  auto writeA = [&](int buf) {
    char* bh = (char*)&As_hi[buf][0][0];
    char* bl = (char*)&As_lo[buf][0][0];
    short4 h, l;
    split2(va0.x, (unsigned short&)h.x, (unsigned short&)l.x);
    split2(va0.y, (unsigned short&)h.y, (unsigned short&)l.y);
    split2(va0.z, (unsigned short&)h.z, (unsigned short&)l.z);
    split2(va0.w, (unsigned short&)h.w, (unsigned short&)l.w);
    *reinterpret_cast<short4*>(bh + arow * 64 + wbyte) = h;
    *reinterpret_cast<short4*>(bl + arow * 64 + wbyte) = l;
    split2(va1.x, (unsigned short&)h.x, (unsigned short&)l.x);
    split2(va1.y, (unsigned short&)h.y, (unsigned short&)l.y);
    split2(va1.z, (unsigned short&)h.z, (unsigned short&)l.z);
    split2(va1.w, (unsigned short&)h.w, (unsigned short&)l.w);
    *reinterpret_cast<short4*>(bh + (64 + arow) * 64 + wbyte) = h;
    *reinterpret_cast<short4*>(bl + (64 + arow) * 64 + wbyte) = l;
  };

  stageB(0, 0);
  loadA(0);
  writeA(0);
  __syncthreads();

  for (int ks = 0; ks < 25; ++ks) {
    const int cur = ks & 1, nxt = cur ^ 1;
    const bool more = (ks + 1 < 25);
    if (more) {
      stageB(ks + 1, nxt);
      loadA(ks + 1);
    }
    short8 ah[4], al[4], bh[2], bl[2];
    #pragma unroll
    for (int i = 0; i < 4; ++i) {
      ah[i] = *reinterpret_cast<const short8*>(&As_hi[cur][wr * 64 + i * 16 + fr][csw]);
      al[i] = *reinterpret_cast<const short8*>(&As_lo[cur][wr * 64 + i * 16 + fr][csw]);
    }
    #pragma unroll
    for (int j = 0; j < 2; ++j) {
      bh[j] = *reinterpret_cast<const short8*>(&Bs_hi[cur][wc * 32 + j * 16 + fr][csw]);
      bl[j] = *reinterpret_cast<const short8*>(&Bs_lo[cur][wc * 32 + j * 16 + fr][csw]);
    }
    __builtin_amdgcn_s_setprio(1);
    #pragma unroll
    for (int i = 0; i < 4; ++i)
      #pragma unroll
      for (int j = 0; j < 2; ++j) {
        acc[i][j] = __builtin_amdgcn_mfma_f32_16x16x32_bf16(ah[i], bh[j], acc[i][j], 0, 0, 0);
        acc[i][j] = __builtin_amdgcn_mfma_f32_16x16x32_bf16(al[i], bh[j], acc[i][j], 0, 0, 0);
        acc[i][j] = __builtin_amdgcn_mfma_f32_16x16x32_bf16(ah[i], bl[j], acc[i][j], 0, 0, 0);
      }
    __builtin_amdgcn_s_setprio(0);
    if (more) writeA(nxt);
    __syncthreads();
  }

  #pragma unroll
  for (int j = 0; j < 2; ++j) {
    const int n = n0 + wc * 32 + j * 16 + (lane & 15);
    if (n >= NH1) continue;
    const float bn = bias[n];
    #pragma unroll
    for (int i = 0; i < 4; ++i) {
      const int mb = m0 + wr * 64 + i * 16 + (lane >> 4) * 4;
      #pragma unroll
      for (int r = 0; r < 4; ++r) {
        float v = fmaxf(acc[i][j][r] + bn, 0.f);
        unsigned short h, l;
        split2(v, h, l);
        Ohi[(size_t)(mb + r) * NH1 + n] = h;
        Olo[(size_t)(mb + r) * NH1 + n] = l;
      }
    }
  }
}

// ---------------------------------------------------------------------------
// Stage 2 (8-wave + hoisted stage descriptors + T5): z_e = h1 @ W2^T + b2.
// ---------------------------------------------------------------------------
__global__ __launch_bounds__(512) void gemm2_split(
    const unsigned short* __restrict__ Ahi, const unsigned short* __restrict__ Alo,
    const unsigned short* __restrict__ Bhi, const unsigned short* __restrict__ Blo,
    const unsigned short* __restrict__ zp, const float* __restrict__ bias,
    float* __restrict__ Of)
{
  __shared__ __align__(16) short As_hi[2][128][32];
  __shared__ __align__(16) short As_lo[2][128][32];
  __shared__ __align__(16) short Bs_hi[2][128][32];
  __shared__ __align__(16) short Bs_lo[2][128][32];
  const int tid = threadIdx.x;
  const int lane = tid & 63, wid = tid >> 6;
  const int wr = wid >> 2, wc = wid & 3;
  const int bid = blockIdx.x;
  const int sw = (bid & 7) * 128 + (bid >> 3);
  const int n0 = (sw & 1) * 128;
  const int m0 = (sw >> 1) * 128;
  const int rr = lane >> 2;
  const int kswz = KSWZ(lane);
  const int csw = CSW(lane);
  const int fr = lane & 15;

  f32x4 acc[4][2];
  #pragma unroll
  for (int i = 0; i < 4; ++i)
    #pragma unroll
    for (int j = 0; j < 2; ++j) acc[i][j] = (f32x4){0.f, 0.f, 0.f, 0.f};

  const unsigned short* srcb[4];
  char* dstb[4];
  bool isAt[4];
  #pragma unroll
  for (int q = 0; q < 4; ++q) {
    const int c = wid * 4 + q;                    // 0..31
    const int tile = c >> 3, sub = c & 7;
    const unsigned short* G;
    int rbase, ld;
    if (tile == 0)      { G = Ahi; rbase = m0; ld = 400; }
    else if (tile == 1) { G = Alo; rbase = m0; ld = 400; }
    else if (tile == 2) { G = Bhi; rbase = n0; ld = 416; }
    else                { G = Blo; rbase = n0; ld = 416; }
    srcb[q] = G + (size_t)(rbase + sub * 16 + rr) * ld + kswz;
    char* Lt = (tile == 0) ? (char*)&As_hi[0][0][0] : (tile == 1) ? (char*)&As_lo[0][0][0]
             : (tile == 2) ? (char*)&Bs_hi[0][0][0] : (char*)&Bs_lo[0][0][0];
    dstb[q] = Lt + sub * 1024;
    isAt[q] = (tile < 2);
  }
  const bool tailz = (kswz >= 16);   // only step k0=384 has 384+kswz >= 400

  auto stage = [&](int ks, int buf) {
    const int k0 = ks * 32;
    const bool ztail = (k0 == 384) && tailz;
    #pragma unroll
    for (int q = 0; q < 4; ++q) {
      const unsigned short* src = srcb[q] + k0;
      if (isAt[q] && ztail) src = zp;
      gload_lds16(src, dstb[q] + buf * 8192);
    }
  };

  stage(0, 0);
  __syncthreads();

  for (int ks = 0; ks < 13; ++ks) {
    const int cur = ks & 1;
    if (ks + 1 < 13) stage(ks + 1, cur ^ 1);
    short8 ah[4], al[4], bh[2], bl[2];
    #pragma unroll
    for (int i = 0; i < 4; ++i) {
      ah[i] = *reinterpret_cast<const short8*>(&As_hi[cur][wr * 64 + i * 16 + fr][csw]);
      al[i] = *reinterpret_cast<const short8*>(&As_lo[cur][wr * 64 + i * 16 + fr][csw]);
    }
    #pragma unroll
    for (int j = 0; j < 2; ++j) {
      bh[j] = *reinterpret_cast<const short8*>(&Bs_hi[cur][wc * 32 + j * 16 + fr][csw]);
      bl[j] = *reinterpret_cast<const short8*>(&Bs_lo[cur][wc * 32 + j * 16 + fr][csw]);
    }
    __builtin_amdgcn_s_setprio(1);
    #pragma unroll
    for (int i = 0; i < 4; ++i)
      #pragma unroll
      for (int j = 0; j < 2; ++j) {
        acc[i][j] = __builtin_amdgcn_mfma_f32_16x16x32_bf16(ah[i], bh[j], acc[i][j], 0, 0, 0);
        acc[i][j] = __builtin_amdgcn_mfma_f32_16x16x32_bf16(al[i], bh[j], acc[i][j], 0, 0, 0);
        acc[i][j] = __builtin_amdgcn_mfma_f32_16x16x32_bf16(ah[i], bl[j], acc[i][j], 0, 0, 0);
      }
    __builtin_amdgcn_s_setprio(0);
    __syncthreads();
  }

  #pragma unroll
  for (int j = 0; j < 2; ++j) {
    const int n = n0 + wc * 32 + j * 16 + (lane & 15);
    if (n >= NH) continue;
    const float bn = bias[n];
    #pragma unroll
    for (int i = 0; i < 4; ++i) {
      const int mb = m0 + wr * 64 + i * 16 + (lane >> 4) * 4;
      #pragma unroll
      for (int r = 0; r < 4; ++r)
        Of[(size_t)(mb + r) * NH + n] = acc[i][j][r] + bn;
    }
  }
}

// ---------------------------------------------------------------------------
// Stage 3 (8-wave + T5): h3 = relu(emb_bf @ W3p^T + b3) -> bf16.
// ---------------------------------------------------------------------------
__global__ __launch_bounds__(512) void gemm3_mfma(
    const unsigned short* __restrict__ A,   // emb_bf: NB x 200
    const __hip_bfloat16* __restrict__ Bp,  // W3p: 512 x 224
    const float* __restrict__ bias, __hip_bfloat16* __restrict__ H3)
{
  __shared__ __align__(16) short As[2][128][32];
  __shared__ __align__(16) short Bs[2][128][32];
  const int tid = threadIdx.x;
  const int lane = tid & 63, wid = tid >> 6;
  const int wr = wid >> 2, wc = wid & 3;
  const int bid = blockIdx.x;
  const int sw = (bid & 7) * 256 + (bid >> 3);
  const int n0 = (sw & 3) * 128;
  const int m0 = (sw >> 2) * 128;
  const int rr = lane >> 2;
  const int kswz = KSWZ(lane);
  const int csw = CSW(lane);
  const int fr = lane & 15;
  const short* Ag = (const short*)A;
  const short* Bg = (const short*)Bp;

  f32x4 acc[4][2];
  #pragma unroll
  for (int i = 0; i < 4; ++i)
    #pragma unroll
    for (int j = 0; j < 2; ++j) acc[i][j] = (f32x4){0.f, 0.f, 0.f, 0.f};

  auto stage = [&](int ks, int buf) {
    const int k0 = ks * 32;
    #pragma unroll
    for (int c = 0; c < 2; ++c) {
      const int ch = wid * 2 + c;
      if (ch < 8)
        gload_lds16(Ag + (size_t)(m0 + ch * 16 + rr) * 200 + k0 + kswz,
                    (char*)&As[buf][0][0] + ch * 1024);
      else
        gload_lds16(Bg + (size_t)(n0 + (ch - 8) * 16 + rr) * 224 + k0 + kswz,
                    (char*)&Bs[buf][0][0] + (ch - 8) * 1024);
    }
  };

  stage(0, 0);
  __syncthreads();
  for (int ks = 0; ks < 7; ++ks) {
    const int cur = ks & 1;
    if (ks + 1 < 7) stage(ks + 1, cur ^ 1);
    short8 af[4], bf[2];
    #pragma unroll
    for (int i = 0; i < 4; ++i)
      af[i] = *reinterpret_cast<const short8*>(&As[cur][wr * 64 + i * 16 + fr][csw]);
    #pragma unroll
    for (int j = 0; j < 2; ++j)
      bf[j] = *reinterpret_cast<const short8*>(&Bs[cur][wc * 32 + j * 16 + fr][csw]);
    __builtin_amdgcn_s_setprio(1);
    #pragma unroll
    for (int i = 0; i < 4; ++i)
      #pragma unroll
      for (int j = 0; j < 2; ++j)
        acc[i][j] = __builtin_amdgcn_mfma_f32_16x16x32_bf16(af[i], bf[j], acc[i][j], 0, 0, 0);
    __builtin_amdgcn_s_setprio(0);
    __syncthreads();
  }

  #pragma unroll
  for (int j = 0; j < 2; ++j) {
    const int n = n0 + wc * 32 + j * 16 + (lane & 15);
    if (n >= NH1) continue;
    const float bn = bias[n];
    #pragma unroll
    for (int i = 0; i < 4; ++i) {
      const int mb = m0 + wr * 64 + i * 16 + (lane >> 4) * 4;
      #pragma unroll
      for (int r = 0; r < 4; ++r)
        H3[(size_t)(mb + r) * NH1 + n] = __float2bfloat16(fmaxf(acc[i][j][r] + bn, 0.f));
    }
  }
}

// ---------------------------------------------------------------------------
// Stage 5 (8-wave + T5): recon = tanh(h3 @ W4p^T + b4). Fast tanh.
// ---------------------------------------------------------------------------
__global__ __launch_bounds__(512) void gemm5_mfma(
    const __hip_bfloat16* __restrict__ A,   // h3: NB x 400
    const __hip_bfloat16* __restrict__ Bp,  // W4p: 896 x 416
    const float* __restrict__ bias, float* __restrict__ C)
{
  __shared__ __align__(16) short As[2][128][32];
  __shared__ __align__(16) short Bs[2][128][32];
  const int tid = threadIdx.x;
  const int lane = tid & 63, wid = tid >> 6;
  const int wr = wid >> 2, wc = wid & 3;
  const int bid = blockIdx.x;
  const int sw = (bid & 7) * 448 + (bid >> 3);
  const int n0 = (sw % 7) * 128;
  const int m0 = (sw / 7) * 128;
  const int rr = lane >> 2;
  const int kswz = KSWZ(lane);
  const int csw = CSW(lane);
  const int fr = lane & 15;
  const short* Ag = (const short*)A;
  const short* Bg = (const short*)Bp;

  f32x4 acc[4][2];
  #pragma unroll
  for (int i = 0; i < 4; ++i)
    #pragma unroll
    for (int j = 0; j < 2; ++j) acc[i][j] = (f32x4){0.f, 0.f, 0.f, 0.f};

  auto stage = [&](int ks, int buf) {
    const int k0 = ks * 32;
    #pragma unroll
    for (int c = 0; c < 2; ++c) {
      const int ch = wid * 2 + c;
      if (ch < 8)
        gload_lds16(Ag + (size_t)(m0 + ch * 16 + rr) * 400 + k0 + kswz,
                    (char*)&As[buf][0][0] + ch * 1024);
      else
        gload_lds16(Bg + (size_t)(n0 + (ch - 8) * 16 + rr) * 416 + k0 + kswz,
                    (char*)&Bs[buf][0][0] + (ch - 8) * 1024);
    }
  };

  stage(0, 0);
  __syncthreads();
  for (int ks = 0; ks < 13; ++ks) {
    const int cur = ks & 1;
    if (ks + 1 < 13) stage(ks + 1, cur ^ 1);
    short8 af[4], bf[2];
    #pragma unroll
    for (int i = 0; i < 4; ++i)
      af[i] = *reinterpret_cast<const short8*>(&As[cur][wr * 64 + i * 16 + fr][csw]);
    #pragma unroll
    for (int j = 0; j < 2; ++j)
      bf[j] = *reinterpret_cast<const short8*>(&Bs[cur][wc * 32 + j * 16 + fr][csw]);
    __builtin_amdgcn_s_setprio(1);
    #pragma unroll
    for (int i = 0; i < 4; ++i)
      #pragma unroll
      for (int j = 0; j < 2; ++j)
        acc[i][j] = __builtin_amdgcn_mfma_f32_16x16x32_bf16(af[i], bf[j], acc[i][j], 0, 0, 0);
    __builtin_amdgcn_s_setprio(0);
    __syncthreads();
  }

  #pragma unroll
  for (int j = 0; j < 2; ++j) {
    const int n = n0 + wc * 32 + j * 16 + (lane & 15);
    if (n >= NIN) continue;
    const float bn = bias[n];
    #pragma unroll
    for (int i = 0; i < 4; ++i) {
      const int mb = m0 + wr * 64 + i * 16 + (lane >> 4) * 4;
      #pragma unroll
      for (int r = 0; r < 4; ++r) {
        const float zv = acc[i][j][r] + bn;
        const float t = __expf(2.0f * zv);
        C[(size_t)(mb + r) * NIN + n] = 1.0f - __fdividef(2.0f, t + 1.0f);
      }
    }
  }
}

// ---------------------------------------------------------------------------
// Merged weight prep + workspace init (memset folded in).
// ---------------------------------------------------------------------------
__global__ __launch_bounds__(256) void prep_all(
    const float* __restrict__ W1, const float* __restrict__ W2,
    const float* __restrict__ W3, const float* __restrict__ W4,
    unsigned short* __restrict__ W1ph, unsigned short* __restrict__ W1pl,
    unsigned short* __restrict__ W2ph, unsigned short* __restrict__ W2pl,
    __hip_bfloat16* __restrict__ W3p, __hip_bfloat16* __restrict__ W4p,
    int* __restrict__ scount, unsigned short* __restrict__ zp,
    unsigned int* __restrict__ sflag)
{
  const int i = blockIdx.x * 256 + threadIdx.x;
  // workspace init (replaces hipMemsetAsync)
  if (i == 0) *scount = 0;
  if (i < 128) zp[i] = 0;
  if (i < NB) sflag[i] = 0u;

  if (i < 409600) {                       // W1p: 512 x 800
    const int n = i / 800, k = i % 800;
    const float v = (n < NH1 && k < NIN) ? W1[(size_t)n * NIN + k] : 0.f;
    unsigned short h, l; split2(v, h, l);
    W1ph[i] = h; W1pl[i] = l;
  } else if (i < 516096) {                // W2p: 256 x 416
    const int j = i - 409600;
    const int n = j / 416, k = j % 416;
    const float v = (n < NH && k < NH1) ? W2[(size_t)n * NH1 + k] : 0.f;
    unsigned short h, l; split2(v, h, l);
    W2ph[j] = h; W2pl[j] = l;
  } else if (i < 888832) {                // W4p: 896 x 416
    const int j = i - 516096;
    const int n = j / 416, k = j % 416;
    const float v = (n < NIN && k < NH1) ? W4[(size_t)n * NH1 + k] : 0.f;
    W4p[j] = __float2bfloat16(v);
  } else if (i < 1003520) {               // W3p: 512 x 224
    const int j = i - 888832;
    const int n = j / 224, k = j % 224;
    const float v = (n < NH1 && k < NH) ? W3[(size_t)n * NH + k] : 0.f;
    W3p[j] = __float2bfloat16(v);
  }
}

// ---------------------------------------------------------------------------
// Quantization (LDS-tiled): one block per 16 samples, 320 threads.
// ---------------------------------------------------------------------------
__global__ __launch_bounds__(320) void quant_kernel(
    const float* __restrict__ z_e, const float* __restrict__ cb,
    float* __restrict__ emb, unsigned short* __restrict__ ebf,
    unsigned int* __restrict__ sflag, int* __restrict__ scount,
    int* __restrict__ slist)
{
  __shared__ float zsl[16 * NH];
  __shared__ double cs[KD][KD];
  __shared__ double chalf[KD];
  __shared__ unsigned short cbf[KD][KD];
  const int tid = threadIdx.x;
  if (tid < KD * KD) {
    const double c = (double)cb[tid];
    cs[tid / KD][tid % KD] = c;
    cbf[tid / KD][tid % KD] = f2bf((float)c);
  }
  __syncthreads();
  if (tid < KD) {
    double s = 0.0;
    #pragma unroll
    for (int k = 0; k < KD; ++k) s += cs[tid][k] * cs[tid][k];
    chalf[tid] = 0.5 * s;
  }

  const int b0 = blockIdx.x * 16;
  for (int t = tid; t < 16 * NH; t += 320)
    zsl[t] = z_e[(size_t)b0 * NH + t];
  __syncthreads();

  const int s16 = tid / NG;           // 0..15
  const int g = tid % NG;
  const int b = b0 + s16;
  const float* zrow = &zsl[s16 * NH + g];
  double v[KD];
  #pragma unroll
  for (int k = 0; k < KD; ++k) v[k] = (double)zrow[k * NG];

  int best = 0; double bt = 1e300, bt2 = 1e300;
  #pragma unroll
  for (int j = 0; j < KD; ++j) {
    double t = chalf[j];
    #pragma unroll
    for (int k = 0; k < KD; ++k) t -= v[k] * cs[j][k];
    if (t < bt) { bt2 = bt; bt = t; best = j; }
    else if (t < bt2) { bt2 = t; }
  }
  float* ep = emb + (size_t)b * NH + g;
  unsigned short* eb = ebf + (size_t)b * NH + g;
  #pragma unroll
  for (int k = 0; k < KD; ++k) {
    ep[k * NG] = (float)cs[best][k];
    eb[k * NG] = cbf[best][k];
  }
  if (bt2 - bt < TAU) {
    if (atomicExch(&sflag[b], 1u) == 0u)
      slist[atomicAdd(scount, 1)] = b;
  }
}

// ---------------------------------------------------------------------------
// Exact f64 repair, one sample per block; rewrites emb + ebf.
// ---------------------------------------------------------------------------
__global__ __launch_bounds__(256) void repair_kernel(
    const float* __restrict__ x, const float* __restrict__ W1,
    const float* __restrict__ b1, const float* __restrict__ W2,
    const float* __restrict__ b2, const float* __restrict__ cb,
    const int* __restrict__ slist, const int* __restrict__ scount,
    float* __restrict__ emb, unsigned short* __restrict__ ebf)
{
  __shared__ double h1s[NH1];
  __shared__ double zs[NH];
  __shared__ double cs[KD][KD];
  __shared__ double chalf[KD];
  const int tid = threadIdx.x;
  const int lane = tid & 63, wv = tid >> 6;
  if (tid < KD * KD) cs[tid / KD][tid % KD] = (double)cb[tid];
  __syncthreads();
  if (tid < KD) {
    double s = 0.0;
    #pragma unroll
    for (int k = 0; k < KD; ++k) s += cs[tid][k] * cs[tid][k];
    chalf[tid] = 0.5 * s;
  }

  int S = *scount; if (S > NB) S = NB;

  for (int si = blockIdx.x; si < S; si += gridDim.x) {
    const int b = slist[si];
    double xr[4][4];
    #pragma unroll
    for (int it = 0; it < 4; ++it) {
      const int c4 = it * 64 + lane;
      if (c4 < 196) {
        float4 v = reinterpret_cast<const float4*>(x + (size_t)b * NIN)[c4];
        xr[it][0] = v.x; xr[it][1] = v.y; xr[it][2] = v.z; xr[it][3] = v.w;
      } else {
        xr[it][0] = xr[it][1] = xr[it][2] = xr[it][3] = 0.0;
      }
    }
    for (int j = wv; j < NH1; j += 4) {
      const float4* wr = reinterpret_cast<const float4*>(W1 + (size_t)j * NIN);
      double s0 = 0, s1 = 0, s2 = 0, s3 = 0;
      #pragma unroll
      for (int it = 0; it < 4; ++it) {
        const int c4 = it * 64 + lane;
        if (c4 < 196) {
          float4 w = wr[c4];
          s0 = fma(xr[it][0], (double)w.x, s0);
          s1 = fma(xr[it][1], (double)w.y, s1);
          s2 = fma(xr[it][2], (double)w.z, s2);
          s3 = fma(xr[it][3], (double)w.w, s3);
        }
      }
      double s = (s0 + s1) + (s2 + s3);
      #pragma unroll
      for (int off = 32; off > 0; off >>= 1) s += __shfl_down(s, off);
      if (lane == 0) { double h = s + (double)b1[j]; h1s[j] = h > 0.0 ? h : 0.0; }
    }
    __syncthreads();
    double hr[2][4];
    #pragma unroll
    for (int it = 0; it < 2; ++it) {
      const int c4 = it * 64 + lane;
      if (c4 < 100) {
        hr[it][0] = h1s[4 * c4 + 0]; hr[it][1] = h1s[4 * c4 + 1];
        hr[it][2] = h1s[4 * c4 + 2]; hr[it][3] = h1s[4 * c4 + 3];
      } else {
        hr[it][0] = hr[it][1] = hr[it][2] = hr[it][3] = 0.0;
      }
    }
    for (int n = wv; n < NH; n += 4) {
      const float4* wr = reinterpret_cast<const float4*>(W2 + (size_t)n * NH1);
      double s0 = 0, s1 = 0, s2 = 0, s3 = 0;
      #pragma unroll
      for (int it = 0; it < 2; ++it) {
        const int c4 = it * 64 + lane;
        if (c4 < 100) {
          float4 w = wr[c4];
          s0 = fma(hr[it][0], (double)w.x, s0);
          s1 = fma(hr[it][1], (double)w.y, s1);
          s2 = fma(hr[it][2], (double)w.z, s2);
          s3 = fma(hr[it][3], (double)w.w, s3);
        }
      }
      double s = (s0 + s1) + (s2 + s3);
      #pragma unroll
      for (int off = 32; off > 0; off >>= 1) s += __shfl_down(s, off);
      if (lane == 0) zs[n] = s + (double)b2[n];
    }
    __syncthreads();
    if (tid < NG) {
      const int g = tid;
      int best = 0; double bt = 1e300;
      #pragma unroll
      for (int j = 0; j < KD; ++j) {
        double t = chalf[j];
        #pragma unroll
        for (int k = 0; k < KD; ++k) t -= zs[k * NG + g] * cs[j][k];
        if (t < bt) { bt = t; best = j; }
      }
      #pragma unroll
      for (int k = 0; k < KD; ++k) {
        const float cv = (float)cs[best][k];
        emb[(size_t)b * NH + k * NG + g] = cv;
        ebf[(size_t)b * NH + k * NG + g] = f2bf(cv);
      }
    }
    __syncthreads();
  }
}

extern "C" void kernel_launch(void* const* d_in, const int* in_sizes, int n_in,
                              void* d_out, int out_size, void* d_ws, size_t ws_size,
                              hipStream_t stream) {
  const float* x  = (const float*)d_in[0];
  const float* W1 = (const float*)d_in[1];
  const float* b1 = (const float*)d_in[2];
  const float* W2 = (const float*)d_in[3];
  const float* b2 = (const float*)d_in[4];
  const float* W3 = (const float*)d_in[5];
  const float* b3 = (const float*)d_in[6];
  const float* W4 = (const float*)d_in[7];
  const float* b4 = (const float*)d_in[8];
  const float* cb = (const float*)d_in[9];

  float* out   = (float*)d_out;
  float* recon = out;                              // NB x 784 (written last)
  float* z_e   = out + (size_t)NB * NIN;           // NB x 200
  float* emb   = z_e + (size_t)NB * NH;            // NB x 200

  unsigned short* h1_lo  = (unsigned short*)emb;   // dead before quant writes emb
  unsigned short* emb_bf = (unsigned short*)recon; // dead recon region

  char* ws = (char*)d_ws;
  int*            scount = (int*)ws;                            // 4 B
  unsigned short* zp    = (unsigned short*)(ws + 256);          // 256 B zeros
  unsigned int*   sflag = (unsigned int*)(ws + 4096);           // 256 KB
  __hip_bfloat16* W3p   = (__hip_bfloat16*)(ws + (1u << 20));   // 512x224
  int*            slist = (int*)(ws + (4u << 20));              // 256 KB
  __hip_bfloat16* W4p   = (__hip_bfloat16*)(ws + (6u << 20));   // 896x416
  unsigned short* W1ph  = (unsigned short*)(ws + (7u << 20));   // 512x800
  unsigned short* W1pl  = (unsigned short*)(ws + (9u << 20));
  unsigned short* W2ph  = (unsigned short*)(ws + (11u << 20));  // 256x416
  unsigned short* W2pl  = (unsigned short*)(ws + (12u << 20));
  unsigned short* h1_hi = (unsigned short*)(ws + (16u << 20));  // NB x 400 bf16
  __hip_bfloat16* h3    = (__hip_bfloat16*)(ws + (16u << 20));  // reuses h1_hi (dead)

  dim3 blk(256);
  prep_all<<<3920, blk, 0, stream>>>(W1, W2, W3, W4, W1ph, W1pl, W2ph, W2pl,
                                     W3p, W4p, scount, zp, sflag);

  // stage 1: h1 = relu(x @ W1^T + b1) -> split bf16 (8-wave, fused conversion)
  gemm1_fused<<<2048, dim3(512), 0, stream>>>(x, W1ph, W1pl, b1, h1_hi, h1_lo);
  // stage 2: z_e = h1 @ W2^T + b2 (8-wave)
  gemm2_split<<<1024, dim3(512), 0, stream>>>(h1_hi, h1_lo, W2ph, W2pl, zp, b2, z_e);

  // stage 3: quantize (LDS-tiled, +bf16 emb, inline compaction), repair
  quant_kernel<<<NB / 16, dim3(320), 0, stream>>>(z_e, cb, emb, emb_bf, sflag, scount, slist);
  repair_kernel<<<1024, blk, 0, stream>>>(x, W1, b1, W2, b2, cb, slist, scount, emb, emb_bf);

  // stage 4: h3 = relu(emb_bf @ W3p^T + b3) -> bf16 (8-wave)
  gemm3_mfma<<<2048, dim3(512), 0, stream>>>(emb_bf, W3p, b3, h3);
  // stage 5: recon = tanh(h3 @ W4p^T + b4) (8-wave)
  gemm5_mfma<<<3584, dim3(512), 0, stream>>>(h3, W4p, b4, recon);
}